// Round 1
// baseline (264.091 us; speedup 1.0000x reference)
//
#include <hip/hip_runtime.h>
#include <stdint.h>

#define SEQ   4096
#define DIM   256
#define HDIM  32
#define HEADS 8
#define W3    768
#define LOG2E 1.4426950408889634f

typedef float  f32x4  __attribute__((ext_vector_type(4)));
typedef short  bf16x8 __attribute__((ext_vector_type(8)));

__device__ __forceinline__ unsigned short f2bf(float f) {
    union { float f; uint32_t u; } v; v.f = f;
    uint32_t u = v.u;
    uint32_t r = (u + 0x7FFFu + ((u >> 16) & 1u)) >> 16;
    return (unsigned short)r;
}

// ---------------- prep: casts + weight transposes ----------------
__global__ __launch_bounds__(256) void prep_kernel(
    const float* __restrict__ x, const float* __restrict__ wqkv,
    const float* __restrict__ wout,
    unsigned short* __restrict__ xb,   // [SEQ][DIM] bf16
    unsigned short* __restrict__ wt,   // [W3][DIM]  bf16  (= w_qkv^T)
    unsigned short* __restrict__ wot)  // [DIM][DIM] bf16  (= w_out^T)
{
    const int NX = SEQ * DIM;
    const int NW = DIM * W3;
    const int NO = DIM * DIM;
    const int total = NX + NW + NO;
    for (int i = blockIdx.x * blockDim.x + threadIdx.x; i < total;
         i += gridDim.x * blockDim.x) {
        if (i < NX) {
            xb[i] = f2bf(x[i]);
        } else if (i < NX + NW) {
            int j = i - NX;
            int col = j >> 8;          // 0..767  (output row of wt)
            int k   = j & 255;         // 0..255
            wt[j] = f2bf(wqkv[k * W3 + col]);
        } else {
            int j = i - NX - NW;
            int col = j >> 8;
            int k   = j & 255;
            wot[j] = f2bf(wout[k * DIM + col]);
        }
    }
}

// ---------------- QKV projection GEMM (bf16 MFMA) ----------------
// C[4096][768] = xb @ w_qkv + b ; routed into Q (x SCALE), K, V^T layouts.
__global__ __launch_bounds__(256) void qkv_gemm(
    const unsigned short* __restrict__ xb,
    const unsigned short* __restrict__ wt,
    const float* __restrict__ bqkv,
    unsigned short* __restrict__ Qb,   // [H][SEQ][HDIM]
    unsigned short* __restrict__ Kb,   // [H][SEQ][HDIM]
    unsigned short* __restrict__ Vt)   // [H][HDIM][SEQ]
{
    const int wid  = threadIdx.x >> 6;
    const int lane = threadIdx.x & 63;
    const int g    = lane >> 4, li = lane & 15;
    const int row0 = blockIdx.x * 128 + wid * 32;
    const int col0 = blockIdx.y * 64;

    f32x4 acc[2][4];
    #pragma unroll
    for (int t = 0; t < 2; ++t)
        #pragma unroll
        for (int c = 0; c < 4; ++c)
            acc[t][c] = (f32x4){0.f, 0.f, 0.f, 0.f};

    #pragma unroll
    for (int ks = 0; ks < DIM; ks += 32) {
        bf16x8 a[2], b[4];
        #pragma unroll
        for (int t = 0; t < 2; ++t)
            a[t] = *(const bf16x8*)(xb + (size_t)(row0 + 16 * t + li) * DIM + ks + g * 8);
        #pragma unroll
        for (int c = 0; c < 4; ++c)
            b[c] = *(const bf16x8*)(wt + (size_t)(col0 + 16 * c + li) * DIM + ks + g * 8);
        #pragma unroll
        for (int t = 0; t < 2; ++t)
            #pragma unroll
            for (int c = 0; c < 4; ++c)
                acc[t][c] = __builtin_amdgcn_mfma_f32_16x16x32_bf16(a[t], b[c], acc[t][c], 0, 0, 0);
    }

    #pragma unroll
    for (int t = 0; t < 2; ++t)
        #pragma unroll
        for (int c = 0; c < 4; ++c)
            #pragma unroll
            for (int r = 0; r < 4; ++r) {
                int row = row0 + 16 * t + g * 4 + r;
                int col = col0 + 16 * c + li;
                float v = acc[t][c][r] + bqkv[col];
                int sec = col >> 8;
                int cc  = col & 255;
                int hh  = cc >> 5, dd = cc & 31;
                if (sec == 0)
                    Qb[((size_t)hh * SEQ + row) * HDIM + dd] = f2bf(v * 0.0625f);
                else if (sec == 1)
                    Kb[((size_t)hh * SEQ + row) * HDIM + dd] = f2bf(v);
                else
                    Vt[((size_t)hh * HDIM + dd) * SEQ + row] = f2bf(v);
            }
}

// ---------------- flash attention (bf16 MFMA, online softmax) ----------------
__global__ __launch_bounds__(256) void attn_kernel(
    const unsigned short* __restrict__ Qb,
    const unsigned short* __restrict__ Kb,
    const unsigned short* __restrict__ Vt,
    unsigned short* __restrict__ AO)   // [SEQ][DIM] bf16
{
    __shared__ unsigned short Plds[4][32][72];   // per-wave P tile, 16B-aligned rows
    const int wid  = threadIdx.x >> 6;
    const int lane = threadIdx.x & 63;
    const int g    = lane >> 4, li = lane & 15;
    const int head = blockIdx.y;
    const int r0   = blockIdx.x * 128 + wid * 32;

    const unsigned short* Qh = Qb + (size_t)head * SEQ * HDIM;
    const unsigned short* Kh = Kb + (size_t)head * SEQ * HDIM;
    const unsigned short* Vh = Vt + (size_t)head * HDIM * SEQ;

    // Q fragments hoisted: A-frag covers full K=32 (= head dim)
    bf16x8 aq[2];
    #pragma unroll
    for (int t = 0; t < 2; ++t)
        aq[t] = *(const bf16x8*)(Qh + (size_t)(r0 + 16 * t + li) * HDIM + g * 8);

    f32x4 o[2][2];
    #pragma unroll
    for (int t = 0; t < 2; ++t)
        #pragma unroll
        for (int nt = 0; nt < 2; ++nt)
            o[t][nt] = (f32x4){0.f, 0.f, 0.f, 0.f};
    float m[2][4], l[2][4];
    #pragma unroll
    for (int t = 0; t < 2; ++t)
        #pragma unroll
        for (int r = 0; r < 4; ++r) { m[t][r] = -1e30f; l[t][r] = 0.f; }

    const f32x4 zero4 = (f32x4){0.f, 0.f, 0.f, 0.f};

    for (int jb = 0; jb < SEQ; jb += 64) {
        // K B-frags (B = K^T tile; contiguous row reads of K)
        bf16x8 bk[4];
        #pragma unroll
        for (int c = 0; c < 4; ++c)
            bk[c] = *(const bf16x8*)(Kh + (size_t)(jb + 16 * c + li) * HDIM + g * 8);

        f32x4 s[2][4];
        #pragma unroll
        for (int t = 0; t < 2; ++t)
            #pragma unroll
            for (int c = 0; c < 4; ++c)
                s[t][c] = __builtin_amdgcn_mfma_f32_16x16x32_bf16(aq[t], bk[c], zero4, 0, 0, 0);

        #pragma unroll
        for (int t = 0; t < 2; ++t) {
            float sc[4];
            #pragma unroll
            for (int r = 0; r < 4; ++r) {
                float v = fmaxf(fmaxf(s[t][0][r], s[t][1][r]), fmaxf(s[t][2][r], s[t][3][r]));
                v = fmaxf(v, __shfl_xor(v, 1));
                v = fmaxf(v, __shfl_xor(v, 2));
                v = fmaxf(v, __shfl_xor(v, 4));
                v = fmaxf(v, __shfl_xor(v, 8));
                float mn = fmaxf(m[t][r], v);
                sc[r] = exp2f((m[t][r] - mn) * LOG2E);
                m[t][r] = mn;
            }
            #pragma unroll
            for (int r = 0; r < 4; ++r) {
                float acc = 0.f;
                #pragma unroll
                for (int c = 0; c < 4; ++c) {
                    float p = exp2f((s[t][c][r] - m[t][r]) * LOG2E);
                    s[t][c][r] = p;
                    acc += p;
                }
                acc += __shfl_xor(acc, 1);
                acc += __shfl_xor(acc, 2);
                acc += __shfl_xor(acc, 4);
                acc += __shfl_xor(acc, 8);
                l[t][r] = l[t][r] * sc[r] + acc;
            }
            #pragma unroll
            for (int nt = 0; nt < 2; ++nt)
                #pragma unroll
                for (int r = 0; r < 4; ++r)
                    o[t][nt][r] *= sc[r];
            // P -> LDS in A-frag-friendly row-major layout (row = q-local, col = kv-local)
            #pragma unroll
            for (int c = 0; c < 4; ++c)
                #pragma unroll
                for (int r = 0; r < 4; ++r)
                    Plds[wid][16 * t + g * 4 + r][16 * c + li] = f2bf(s[t][c][r]);
        }

        // V B-frags from V^T (contiguous along seq)
        bf16x8 bv[2][2];
        #pragma unroll
        for (int kc = 0; kc < 2; ++kc)
            #pragma unroll
            for (int nt = 0; nt < 2; ++nt)
                bv[kc][nt] = *(const bf16x8*)(Vh + (size_t)(16 * nt + li) * SEQ + jb + kc * 32 + g * 8);

        // PV: A = P (from LDS), accumulate into o
        #pragma unroll
        for (int t = 0; t < 2; ++t)
            #pragma unroll
            for (int kc = 0; kc < 2; ++kc) {
                bf16x8 pa = *(const bf16x8*)(&Plds[wid][16 * t + li][kc * 32 + g * 8]);
                #pragma unroll
                for (int nt = 0; nt < 2; ++nt)
                    o[t][nt] = __builtin_amdgcn_mfma_f32_16x16x32_bf16(pa, bv[kc][nt], o[t][nt], 0, 0, 0);
            }
    }

    #pragma unroll
    for (int t = 0; t < 2; ++t)
        #pragma unroll
        for (int nt = 0; nt < 2; ++nt)
            #pragma unroll
            for (int r = 0; r < 4; ++r) {
                int row = r0 + 16 * t + g * 4 + r;
                int col = head * HDIM + 16 * nt + li;
                AO[(size_t)row * DIM + col] = f2bf(o[t][nt][r] / l[t][r]);
            }
}

// ---------------- output projection GEMM (bf16 MFMA, f32 out) ----------------
__global__ __launch_bounds__(256) void out_gemm(
    const unsigned short* __restrict__ AO,
    const unsigned short* __restrict__ wot,
    const float* __restrict__ bout,
    float* __restrict__ out)
{
    const int wid  = threadIdx.x >> 6;
    const int lane = threadIdx.x & 63;
    const int g    = lane >> 4, li = lane & 15;
    const int row0 = blockIdx.x * 128 + wid * 32;
    const int col0 = blockIdx.y * 64;

    f32x4 acc[2][4];
    #pragma unroll
    for (int t = 0; t < 2; ++t)
        #pragma unroll
        for (int c = 0; c < 4; ++c)
            acc[t][c] = (f32x4){0.f, 0.f, 0.f, 0.f};

    #pragma unroll
    for (int ks = 0; ks < DIM; ks += 32) {
        bf16x8 a[2], b[4];
        #pragma unroll
        for (int t = 0; t < 2; ++t)
            a[t] = *(const bf16x8*)(AO + (size_t)(row0 + 16 * t + li) * DIM + ks + g * 8);
        #pragma unroll
        for (int c = 0; c < 4; ++c)
            b[c] = *(const bf16x8*)(wot + (size_t)(col0 + 16 * c + li) * DIM + ks + g * 8);
        #pragma unroll
        for (int t = 0; t < 2; ++t)
            #pragma unroll
            for (int c = 0; c < 4; ++c)
                acc[t][c] = __builtin_amdgcn_mfma_f32_16x16x32_bf16(a[t], b[c], acc[t][c], 0, 0, 0);
    }

    #pragma unroll
    for (int t = 0; t < 2; ++t)
        #pragma unroll
        for (int c = 0; c < 4; ++c)
            #pragma unroll
            for (int r = 0; r < 4; ++r) {
                int row = row0 + 16 * t + g * 4 + r;
                int col = col0 + 16 * c + li;
                out[(size_t)row * DIM + col] = acc[t][c][r] + bout[col];
            }
}

extern "C" void kernel_launch(void* const* d_in, const int* in_sizes, int n_in,
                              void* d_out, int out_size, void* d_ws, size_t ws_size,
                              hipStream_t stream)
{
    const float* x    = (const float*)d_in[0];
    const float* wqkv = (const float*)d_in[1];
    const float* bqkv = (const float*)d_in[2];
    const float* wout = (const float*)d_in[3];
    const float* bout = (const float*)d_in[4];
    float* out = (float*)d_out;

    // workspace layout (bytes)
    char* ws = (char*)d_ws;
    const size_t OFF_XB  = 0;          // 4096*256 bf16      = 2,097,152
    const size_t OFF_WT  = 2097152;    // 768*256 bf16       =   393,216
    const size_t OFF_WOT = 2490368;    // 256*256 bf16       =   131,072
    const size_t OFF_QB  = 2621440;    // 8*4096*32 bf16     = 2,097,152
    const size_t OFF_KB  = 4718592;
    const size_t OFF_VT  = 6815744;
    const size_t OFF_AO  = 8912896;    // end 11,010,048
    if (ws_size < 11010048) return;    // loud failure rather than corruption

    unsigned short* xb  = (unsigned short*)(ws + OFF_XB);
    unsigned short* wt  = (unsigned short*)(ws + OFF_WT);
    unsigned short* wot = (unsigned short*)(ws + OFF_WOT);
    unsigned short* Qb  = (unsigned short*)(ws + OFF_QB);
    unsigned short* Kb  = (unsigned short*)(ws + OFF_KB);
    unsigned short* Vt  = (unsigned short*)(ws + OFF_VT);
    unsigned short* AO  = (unsigned short*)(ws + OFF_AO);

    hipLaunchKernelGGL(prep_kernel, dim3(2048), dim3(256), 0, stream,
                       x, wqkv, wout, xb, wt, wot);
    hipLaunchKernelGGL(qkv_gemm, dim3(32, 12), dim3(256), 0, stream,
                       xb, wt, bqkv, Qb, Kb, Vt);
    hipLaunchKernelGGL(attn_kernel, dim3(32, 8), dim3(256), 0, stream,
                       Qb, Kb, Vt, AO);
    hipLaunchKernelGGL(out_gemm, dim3(32, 4), dim3(256), 0, stream,
                       AO, wot, bout, out);
}

// Round 2
// 120.928 us; speedup vs baseline: 2.1839x; 2.1839x over previous
//
#include <hip/hip_runtime.h>
#include <stdint.h>

#define SEQ   4096
#define DIM   256
#define HDIM  32
#define HEADS 8
#define W3    768
#define LOG2E 1.4426950408889634f
#define DEFER_THR 8.0f

typedef float  f32x4  __attribute__((ext_vector_type(4)));
typedef short  bf16x8 __attribute__((ext_vector_type(8)));

__device__ __forceinline__ unsigned short f2bf(float f) {
    union { __bf16 h; unsigned short u; } v;
    v.h = (__bf16)f;           // hardware v_cvt on gfx950, RNE
    return v.u;
}

// ---------------- prep: casts + weight transposes ----------------
__global__ __launch_bounds__(256) void prep_kernel(
    const float* __restrict__ x, const float* __restrict__ wqkv,
    const float* __restrict__ wout,
    unsigned short* __restrict__ xb,   // [SEQ][DIM] bf16
    unsigned short* __restrict__ wt,   // [W3][DIM]  bf16  (= w_qkv^T)
    unsigned short* __restrict__ wot)  // [DIM][DIM] bf16  (= w_out^T)
{
    const int NX = SEQ * DIM;
    const int NW = DIM * W3;
    const int NO = DIM * DIM;
    const int total = NX + NW + NO;
    for (int i = blockIdx.x * blockDim.x + threadIdx.x; i < total;
         i += gridDim.x * blockDim.x) {
        if (i < NX) {
            xb[i] = f2bf(x[i]);
        } else if (i < NX + NW) {
            int j = i - NX;
            int col = j >> 8;
            int k   = j & 255;
            wt[j] = f2bf(wqkv[k * W3 + col]);
        } else {
            int j = i - NX - NW;
            int col = j >> 8;
            int k   = j & 255;
            wot[j] = f2bf(wout[k * DIM + col]);
        }
    }
}

// ---------------- QKV projection GEMM (bf16 MFMA) ----------------
__global__ __launch_bounds__(256) void qkv_gemm(
    const unsigned short* __restrict__ xb,
    const unsigned short* __restrict__ wt,
    const float* __restrict__ bqkv,
    unsigned short* __restrict__ Qb,   // [H][SEQ][HDIM], pre-scaled
    unsigned short* __restrict__ Kb,   // [H][SEQ][HDIM]
    unsigned short* __restrict__ Vt)   // [H][HDIM][SEQ]
{
    const int wid  = threadIdx.x >> 6;
    const int lane = threadIdx.x & 63;
    const int g    = lane >> 4, li = lane & 15;
    const int row0 = blockIdx.x * 128 + wid * 32;
    const int col0 = blockIdx.y * 64;

    f32x4 acc[2][4];
    #pragma unroll
    for (int t = 0; t < 2; ++t)
        #pragma unroll
        for (int c = 0; c < 4; ++c)
            acc[t][c] = (f32x4){0.f, 0.f, 0.f, 0.f};

    #pragma unroll
    for (int ks = 0; ks < DIM; ks += 32) {
        bf16x8 a[2], b[4];
        #pragma unroll
        for (int t = 0; t < 2; ++t)
            a[t] = *(const bf16x8*)(xb + (size_t)(row0 + 16 * t + li) * DIM + ks + g * 8);
        #pragma unroll
        for (int c = 0; c < 4; ++c)
            b[c] = *(const bf16x8*)(wt + (size_t)(col0 + 16 * c + li) * DIM + ks + g * 8);
        #pragma unroll
        for (int t = 0; t < 2; ++t)
            #pragma unroll
            for (int c = 0; c < 4; ++c)
                acc[t][c] = __builtin_amdgcn_mfma_f32_16x16x32_bf16(a[t], b[c], acc[t][c], 0, 0, 0);
    }

    #pragma unroll
    for (int t = 0; t < 2; ++t)
        #pragma unroll
        for (int c = 0; c < 4; ++c)
            #pragma unroll
            for (int r = 0; r < 4; ++r) {
                int row = row0 + 16 * t + g * 4 + r;
                int col = col0 + 16 * c + li;
                float v = acc[t][c][r] + bqkv[col];
                int sec = col >> 8;
                int cc  = col & 255;
                int hh  = cc >> 5, dd = cc & 31;
                if (sec == 0)
                    Qb[((size_t)hh * SEQ + row) * HDIM + dd] = f2bf(v * 0.0625f);
                else if (sec == 1)
                    Kb[((size_t)hh * SEQ + row) * HDIM + dd] = f2bf(v);
                else
                    Vt[((size_t)hh * HDIM + dd) * SEQ + row] = f2bf(v);
            }
}

// ------- flash attention, KV-split partials (bf16 MFMA, online softmax) -------
__global__ __launch_bounds__(256) void attn_kernel(
    const unsigned short* __restrict__ Qb,
    const unsigned short* __restrict__ Kb,
    const unsigned short* __restrict__ Vt,
    float* __restrict__ Opart,   // [nc][SEQ][DIM] unnormalized
    float* __restrict__ ML,      // [nc][HEADS][SEQ][2]
    int nc)
{
    __shared__ unsigned short Plds[4][32][72];
    const int wid  = threadIdx.x >> 6;
    const int lane = threadIdx.x & 63;
    const int g    = lane >> 4, li = lane & 15;
    const int head = blockIdx.y;
    const int chunk = blockIdx.z;
    const int r0   = blockIdx.x * 128 + wid * 32;
    const int span = SEQ / nc;
    const int jb0 = chunk * span, jb1 = jb0 + span;

    const unsigned short* Qh = Qb + (size_t)head * SEQ * HDIM;
    const unsigned short* Kh = Kb + (size_t)head * SEQ * HDIM;
    const unsigned short* Vh = Vt + (size_t)head * HDIM * SEQ;

    bf16x8 aq[2];
    #pragma unroll
    for (int t = 0; t < 2; ++t)
        aq[t] = *(const bf16x8*)(Qh + (size_t)(r0 + 16 * t + li) * HDIM + g * 8);

    f32x4 o[2][2];
    #pragma unroll
    for (int t = 0; t < 2; ++t)
        #pragma unroll
        for (int nt = 0; nt < 2; ++nt)
            o[t][nt] = (f32x4){0.f, 0.f, 0.f, 0.f};
    float m[2][4], l[2][4];
    #pragma unroll
    for (int t = 0; t < 2; ++t)
        #pragma unroll
        for (int r = 0; r < 4; ++r) { m[t][r] = -1e30f; l[t][r] = 0.f; }

    const f32x4 zero4 = (f32x4){0.f, 0.f, 0.f, 0.f};

    for (int jb = jb0; jb < jb1; jb += 64) {
        bf16x8 bk[4];
        #pragma unroll
        for (int c = 0; c < 4; ++c)
            bk[c] = *(const bf16x8*)(Kh + (size_t)(jb + 16 * c + li) * HDIM + g * 8);

        f32x4 s[2][4];
        #pragma unroll
        for (int t = 0; t < 2; ++t)
            #pragma unroll
            for (int c = 0; c < 4; ++c)
                s[t][c] = __builtin_amdgcn_mfma_f32_16x16x32_bf16(aq[t], bk[c], zero4, 0, 0, 0);

        // per-row tile max
        float rm[2][4];
        #pragma unroll
        for (int t = 0; t < 2; ++t)
            #pragma unroll
            for (int r = 0; r < 4; ++r) {
                float v = fmaxf(fmaxf(s[t][0][r], s[t][1][r]), fmaxf(s[t][2][r], s[t][3][r]));
                v = fmaxf(v, __shfl_xor(v, 1));
                v = fmaxf(v, __shfl_xor(v, 2));
                v = fmaxf(v, __shfl_xor(v, 4));
                v = fmaxf(v, __shfl_xor(v, 8));
                rm[t][r] = v;
            }
        // defer-max: only rescale when some row's max grew past threshold
        int need = 0;
        #pragma unroll
        for (int t = 0; t < 2; ++t)
            #pragma unroll
            for (int r = 0; r < 4; ++r)
                need |= (rm[t][r] > m[t][r] + DEFER_THR);
        if (__any(need)) {
            #pragma unroll
            for (int t = 0; t < 2; ++t) {
                float sc[4];
                #pragma unroll
                for (int r = 0; r < 4; ++r) {
                    float mn = fmaxf(m[t][r], rm[t][r]);
                    sc[r] = __builtin_amdgcn_exp2f((m[t][r] - mn) * LOG2E);
                    m[t][r] = mn;
                    l[t][r] *= sc[r];
                }
                #pragma unroll
                for (int nt = 0; nt < 2; ++nt)
                    #pragma unroll
                    for (int r = 0; r < 4; ++r)
                        o[t][nt][r] *= sc[r];
            }
        }

        #pragma unroll
        for (int t = 0; t < 2; ++t) {
            float nb[4];
            #pragma unroll
            for (int r = 0; r < 4; ++r)
                nb[r] = -m[t][r] * LOG2E;
            #pragma unroll
            for (int r = 0; r < 4; ++r) {
                float p0 = __builtin_amdgcn_exp2f(s[t][0][r] * LOG2E + nb[r]);
                float p1 = __builtin_amdgcn_exp2f(s[t][1][r] * LOG2E + nb[r]);
                float p2 = __builtin_amdgcn_exp2f(s[t][2][r] * LOG2E + nb[r]);
                float p3 = __builtin_amdgcn_exp2f(s[t][3][r] * LOG2E + nb[r]);
                s[t][0][r] = p0; s[t][1][r] = p1; s[t][2][r] = p2; s[t][3][r] = p3;
                float acc = (p0 + p1) + (p2 + p3);
                acc += __shfl_xor(acc, 1);
                acc += __shfl_xor(acc, 2);
                acc += __shfl_xor(acc, 4);
                acc += __shfl_xor(acc, 8);
                l[t][r] += acc;
            }
            #pragma unroll
            for (int c = 0; c < 4; ++c)
                #pragma unroll
                for (int r = 0; r < 4; ++r)
                    Plds[wid][16 * t + g * 4 + r][16 * c + li] = f2bf(s[t][c][r]);
        }

        bf16x8 bv[2][2];
        #pragma unroll
        for (int kc = 0; kc < 2; ++kc)
            #pragma unroll
            for (int nt = 0; nt < 2; ++nt)
                bv[kc][nt] = *(const bf16x8*)(Vh + (size_t)(16 * nt + li) * SEQ + jb + kc * 32 + g * 8);

        #pragma unroll
        for (int t = 0; t < 2; ++t)
            #pragma unroll
            for (int kc = 0; kc < 2; ++kc) {
                bf16x8 pa = *(const bf16x8*)(&Plds[wid][16 * t + li][kc * 32 + g * 8]);
                #pragma unroll
                for (int nt = 0; nt < 2; ++nt)
                    o[t][nt] = __builtin_amdgcn_mfma_f32_16x16x32_bf16(pa, bv[kc][nt], o[t][nt], 0, 0, 0);
            }
    }

    // write unnormalized partials + (m,l)
    float* Oc = Opart + (size_t)chunk * SEQ * DIM;
    #pragma unroll
    for (int t = 0; t < 2; ++t)
        #pragma unroll
        for (int nt = 0; nt < 2; ++nt)
            #pragma unroll
            for (int r = 0; r < 4; ++r) {
                int row = r0 + 16 * t + g * 4 + r;
                int col = head * HDIM + 16 * nt + li;
                Oc[(size_t)row * DIM + col] = o[t][nt][r];
            }
    if (li == 0) {
        #pragma unroll
        for (int t = 0; t < 2; ++t)
            #pragma unroll
            for (int r = 0; r < 4; ++r) {
                int row = r0 + 16 * t + g * 4 + r;
                size_t base = (((size_t)chunk * HEADS + head) * SEQ + row) * 2;
                ML[base]     = m[t][r];
                ML[base + 1] = l[t][r];
            }
    }
}

// ---------------- combine partials -> AO bf16 ----------------
__global__ __launch_bounds__(256) void combine_kernel(
    const float* __restrict__ Opart, const float* __restrict__ ML,
    unsigned short* __restrict__ AO, int nc)
{
    int idx = blockIdx.x * 256 + threadIdx.x;   // over SEQ*DIM/2 pairs
    int row = idx >> 7;
    int cp  = (idx & 127) << 1;
    int head = cp >> 5;
    float M = -1e30f;
    for (int i = 0; i < nc; ++i)
        M = fmaxf(M, ML[(((size_t)i * HEADS + head) * SEQ + row) * 2]);
    float L = 0.f, a0 = 0.f, a1 = 0.f;
    for (int i = 0; i < nc; ++i) {
        const float* mlp = ML + (((size_t)i * HEADS + head) * SEQ + row) * 2;
        float w = __builtin_amdgcn_exp2f((mlp[0] - M) * LOG2E);
        L += mlp[1] * w;
        const float* op = Opart + (size_t)i * SEQ * DIM + (size_t)row * DIM + cp;
        a0 += op[0] * w;
        a1 += op[1] * w;
    }
    float inv = 1.f / L;
    uint32_t pk = (uint32_t)f2bf(a0 * inv) | ((uint32_t)f2bf(a1 * inv) << 16);
    *reinterpret_cast<uint32_t*>(AO + (size_t)row * DIM + cp) = pk;
}

// ---------------- output projection GEMM (bf16 MFMA, f32 out) ----------------
__global__ __launch_bounds__(256) void out_gemm(
    const unsigned short* __restrict__ AO,
    const unsigned short* __restrict__ wot,
    const float* __restrict__ bout,
    float* __restrict__ out)
{
    const int wid  = threadIdx.x >> 6;
    const int lane = threadIdx.x & 63;
    const int g    = lane >> 4, li = lane & 15;
    const int row0 = blockIdx.x * 64 + wid * 16;   // 16 rows per wave
    const int col0 = blockIdx.y * 64;

    f32x4 acc[4];
    #pragma unroll
    for (int c = 0; c < 4; ++c)
        acc[c] = (f32x4){0.f, 0.f, 0.f, 0.f};

    #pragma unroll
    for (int ks = 0; ks < DIM; ks += 32) {
        bf16x8 a = *(const bf16x8*)(AO + (size_t)(row0 + li) * DIM + ks + g * 8);
        bf16x8 b[4];
        #pragma unroll
        for (int c = 0; c < 4; ++c)
            b[c] = *(const bf16x8*)(wot + (size_t)(col0 + 16 * c + li) * DIM + ks + g * 8);
        #pragma unroll
        for (int c = 0; c < 4; ++c)
            acc[c] = __builtin_amdgcn_mfma_f32_16x16x32_bf16(a, b[c], acc[c], 0, 0, 0);
    }

    #pragma unroll
    for (int c = 0; c < 4; ++c)
        #pragma unroll
        for (int r = 0; r < 4; ++r) {
            int row = row0 + g * 4 + r;
            int col = col0 + 16 * c + li;
            out[(size_t)row * DIM + col] = acc[c][r] + bout[col];
        }
}

extern "C" void kernel_launch(void* const* d_in, const int* in_sizes, int n_in,
                              void* d_out, int out_size, void* d_ws, size_t ws_size,
                              hipStream_t stream)
{
    const float* x    = (const float*)d_in[0];
    const float* wqkv = (const float*)d_in[1];
    const float* bqkv = (const float*)d_in[2];
    const float* wout = (const float*)d_in[3];
    const float* bout = (const float*)d_in[4];
    float* out = (float*)d_out;

    char* ws = (char*)d_ws;
    const size_t OFF_XB  = 0;
    const size_t OFF_WT  = 2097152;
    const size_t OFF_WOT = 2490368;
    const size_t OFF_QB  = 2621440;
    const size_t OFF_KB  = 4718592;
    const size_t OFF_VT  = 6815744;
    const size_t OFF_AO  = 8912896;
    const size_t OFF_OP  = 11010048;
    const size_t OP_CH   = (size_t)SEQ * DIM * 4;        // 4 MiB / chunk
    const size_t ML_CH   = (size_t)HEADS * SEQ * 2 * 4;  // 256 KiB / chunk

    int nc = 4;
    while (nc > 1 && OFF_OP + (size_t)nc * (OP_CH + ML_CH) > ws_size) nc >>= 1;
    if (OFF_OP + (size_t)nc * (OP_CH + ML_CH) > ws_size) return;  // loud failure

    unsigned short* xb  = (unsigned short*)(ws + OFF_XB);
    unsigned short* wt  = (unsigned short*)(ws + OFF_WT);
    unsigned short* wot = (unsigned short*)(ws + OFF_WOT);
    unsigned short* Qb  = (unsigned short*)(ws + OFF_QB);
    unsigned short* Kb  = (unsigned short*)(ws + OFF_KB);
    unsigned short* Vt  = (unsigned short*)(ws + OFF_VT);
    unsigned short* AO  = (unsigned short*)(ws + OFF_AO);
    float* Opart = (float*)(ws + OFF_OP);
    float* ML    = (float*)(ws + OFF_OP + (size_t)nc * OP_CH);

    hipLaunchKernelGGL(prep_kernel, dim3(2048), dim3(256), 0, stream,
                       x, wqkv, wout, xb, wt, wot);
    hipLaunchKernelGGL(qkv_gemm, dim3(32, 12), dim3(256), 0, stream,
                       xb, wt, bqkv, Qb, Kb, Vt);
    hipLaunchKernelGGL(attn_kernel, dim3(32, 8, nc), dim3(256), 0, stream,
                       Qb, Kb, Vt, Opart, ML, nc);
    hipLaunchKernelGGL(combine_kernel, dim3(SEQ * DIM / 512), dim3(256), 0, stream,
                       Opart, ML, AO, nc);
    hipLaunchKernelGGL(out_gemm, dim3(SEQ / 64, DIM / 64), dim3(256), 0, stream,
                       AO, wot, bout, out);
}